// Round 3
// baseline (135.288 us; speedup 1.0000x reference)
//
#include <hip/hip_runtime.h>
#include <hip/hip_bf16.h>

// Problem: X-ray forward projection. Volume 128^3 fp32, detector 179x179, 10 views.
// Inputs (fp32/int32 per reference): I_rec [1,1,128,128,128], poses [50,3], idx [10].
// Output (fp32 flat, tuple concatenated): projections [10,179,179] then idx [10].
//
// Geometry (derived from reference, verified algebraically):
//   volume layout vol[c][y][a]: c = spatial_x + 63.5, y index = plane p, a = spatial_z + 63.5
//   sampled y at plane p is exactly p - 0.5  =>  ty = 0.5 always:
//     sample(p) = 0.5*(bilin(slice p-1) + bilin(slice p)) at (c(p), a(p));  p=0: slice -1 is zero-pad
//   ray is linear in p: c(p) = (pdx+63.5) + p*(ex-pdx)/ey,  a(p) = (pdz+63.5) + p*(ez-pdz)/ey
//   weight dx = dist(Pd, E)/ey,  ey in [256,384) > 0
// Round-2 post-mortem established the fp32-in/fp32-out dtype contract (bf16 writes
// scrambled the fp32 out buffer -> absmax == max|ref| == 150 with zero tail).

#define DVOL   128
#define RES    179
#define NPROJ  10

__global__ __launch_bounds__(256) void proj_kernel(
    const float* __restrict__ vol,    // [128,128,128]
    const float* __restrict__ poses,  // [50,3]
    const int* __restrict__ idx,      // [10]
    float* __restrict__ out)          // [10,179,179]
{
    const int gj = blockIdx.x * 64 + (threadIdx.x & 63);  // detector col -> contiguous a-axis
    const int gi = blockIdx.y * 4 + (threadIdx.x >> 6);   // detector row
    const int j  = blockIdx.z;
    if (gi >= RES || gj >= RES) return;

    const int pid = idx[j];
    const float ex = poses[pid * 3 + 0];
    const float ey = poses[pid * 3 + 1];
    const float ez = poses[pid * 3 + 2];

    const float pdx = (float)gi - 89.5f;  // spatial x (volume first axis c)
    const float pdz = (float)gj - 89.5f;  // spatial z (volume last axis a, contiguous)

    const float inv_ey = 1.0f / ey;
    const float sx = (ex - pdx) * inv_ey;   // d(c)/d(p)
    const float sz = (ez - pdz) * inv_ey;   // d(a)/d(p)
    const float ddx = pdx - ex, ddz = pdz - ez;
    const float dxw = sqrtf(ddx * ddx + ey * ey + ddz * ddz) * fabsf(inv_ey);

    const float cb = pdx + 63.5f;  // c at p=0
    const float ab = pdz + 63.5f;  // a at p=0

    float acc = 0.0f;
    for (int p = 0; p < DVOL; ++p) {
        const float cf = fmaf((float)p, sx, cb);
        const float af = fmaf((float)p, sz, ab);
        // Outside [-1, 128) in either axis => all 4 bilinear corners zero-padded.
        if (cf >= -1.0f && cf < 128.0f && af >= -1.0f && af < 128.0f) {
            const float c0f = floorf(cf), a0f = floorf(af);
            const float tc = cf - c0f, ta = af - a0f;
            const int c0 = (int)c0f, a0 = (int)a0f;
            // zero-padding: invalid corner -> weight 0, index clamped (safe load)
            const float wc0 = (c0 >= 0)   ? (1.0f - tc) : 0.0f;
            const float wc1 = (c0 <= 126) ? tc          : 0.0f;
            const float wa0 = (a0 >= 0)   ? (1.0f - ta) : 0.0f;
            const float wa1 = (a0 <= 126) ? ta          : 0.0f;
            const int c0c = c0 < 0 ? 0 : c0;
            const int c1c = c0 >= 127 ? 127 : c0 + 1;
            const int a0c = a0 < 0 ? 0 : a0;
            const int a1c = a0 >= 127 ? 127 : a0 + 1;

            const float w00 = wc0 * wa0, w01 = wc0 * wa1;
            const float w10 = wc1 * wa0, w11 = wc1 * wa1;

            const int base0 = (c0c << 14) + (p << 7);  // slice p, row c0
            const int base1 = (c1c << 14) + (p << 7);  // slice p, row c1

            float s = w00 * vol[base0 + a0c] + w01 * vol[base0 + a1c]
                    + w10 * vol[base1 + a0c] + w11 * vol[base1 + a1c];
            if (p >= 1) {  // slice p-1 is 128 elements below (wave-uniform branch)
                s += w00 * vol[base0 + a0c - 128] + w01 * vol[base0 + a1c - 128]
                   + w10 * vol[base1 + a0c - 128] + w11 * vol[base1 + a1c - 128];
            }
            acc += 0.5f * s;
        }
    }
    out[j * (RES * RES) + gi * RES + gj] = acc * dxw;
}

// Second tuple output: idx passthrough as float (single-dtype fp32 out buffer).
__global__ void idx_kernel(const int* __restrict__ idx, float* __restrict__ out_tail) {
    const int t = threadIdx.x;
    if (t < NPROJ) out_tail[t] = (float)idx[t];
}

extern "C" void kernel_launch(void* const* d_in, const int* in_sizes, int n_in,
                              void* d_out, int out_size, void* d_ws, size_t ws_size,
                              hipStream_t stream) {
    const float* vol   = (const float*)d_in[0];
    const float* poses = (const float*)d_in[1];
    const int*   idx   = (const int*)d_in[2];
    float* out = (float*)d_out;

    dim3 grid(3 /*ceil(179/64)*/, 45 /*ceil(179/4)*/, NPROJ);
    proj_kernel<<<grid, 256, 0, stream>>>(vol, poses, idx, out);

    if (out_size >= RES * RES * NPROJ + NPROJ) {
        idx_kernel<<<1, 64, 0, stream>>>(idx, out + RES * RES * NPROJ);
    }
}